// Round 12
// baseline (498.064 us; speedup 1.0000x reference)
//
#include <hip/hip_runtime.h>

// Problem constants
#define N_NODES_C 100000
#define N_EDGES_C 200000
#define N_INC_C   1600000
#define F_IN_C    128
#define H1_C      64
#define H2_C      128

typedef unsigned int uint;
typedef unsigned short ushort;

// ---------------- workspace layout (units of 4 bytes) ----------------
static constexpr size_t U_HIST_E = 0;          // 200000 (int)   memset [0,300000)
static constexpr size_t U_HIST_N = 200000;     // 100000 (int)
static constexpr size_t U_RPE    = 300000;     // 200001 (int)
static constexpr size_t U_RPN    = 500032;     // 100001 (int)
static constexpr size_t U_BSUM   = 600064;     // 256 (int): e at +0, n at +128
static constexpr size_t U_COEF   = 600320;     // 200000 (float)
static constexpr size_t U_DINV   = 800320;     // 100000 (float)
static constexpr size_t U_RANK_E = 900320;     // 1600000 (int)
static constexpr size_t U_RANK_N = 2500320;    // 1600000 (int)
static constexpr size_t U_CSR_EN = 4100320;    // 1600000 (int)  edge -> node ids
static constexpr size_t U_CSR_NE = 5700320;    // 1600000 (int)  node -> edge ids
static constexpr size_t U_R2     = 7300320;    // 3200000 u32 = node bf16 buf (h1/g1/t2)
static constexpr size_t U_R1     = 10500320;   // 6400000 u32 = edge bf16 buf (e1/s2)
// total = 16900320 * 4 B = 67.6 MB

// ---------------- bf16 helpers (fp32 accumulate, RNE pack) ----------------
__device__ __forceinline__ void unpack2(uint u, float& a, float& b) {
    a = __uint_as_float(u << 16);
    b = __uint_as_float(u & 0xFFFF0000u);
}
__device__ __forceinline__ uint bfr(float f) {
    uint u = __float_as_uint(f);
    return (u + 0x7FFFu + ((u >> 16) & 1u)) >> 16;
}

// ---------------- CSR build ----------------

// histogram + rank, unrolled x4: 8 independent atomics in flight per thread
// (r11 model: hist was wave-latency-bound at 2 atomics/thread; this is the A/B)
__global__ void k_hist_rank(const int* __restrict__ nidx, const int* __restrict__ eidx,
                            int* __restrict__ hist_n, int* __restrict__ hist_e,
                            int* __restrict__ rank_n, int* __restrict__ rank_e) {
    const int n4 = N_INC_C / 4;  // 400000
    int i4 = blockIdx.x * blockDim.x + threadIdx.x;
    int stride = gridDim.x * blockDim.x;
    for (; i4 < n4; i4 += stride) {
        int4 e = reinterpret_cast<const int4*>(eidx)[i4];
        int4 n = reinterpret_cast<const int4*>(nidx)[i4];
        int re0 = atomicAdd(&hist_e[e.x], 1);
        int re1 = atomicAdd(&hist_e[e.y], 1);
        int re2 = atomicAdd(&hist_e[e.z], 1);
        int re3 = atomicAdd(&hist_e[e.w], 1);
        int rn0 = atomicAdd(&hist_n[n.x], 1);
        int rn1 = atomicAdd(&hist_n[n.y], 1);
        int rn2 = atomicAdd(&hist_n[n.z], 1);
        int rn3 = atomicAdd(&hist_n[n.w], 1);
        reinterpret_cast<int4*>(rank_e)[i4] = make_int4(re0, re1, re2, re3);
        reinterpret_cast<int4*>(rank_n)[i4] = make_int4(rn0, rn1, rn2, rn3);
    }
}

#define SCAN_ITEMS 8
#define SCAN_CHUNK 2048  // 256 threads * 8
#define NB_E 98          // ceil(200000/2048)
#define NB_N 49          // ceil(100000/2048)

// merged e+n block-sum stage: blocks [0,NB_E) -> e, [NB_E,NB_E+NB_N) -> n
__global__ __launch_bounds__(256) void k_scan_bs2(const int* __restrict__ hist_e,
                                                  const int* __restrict__ hist_n,
                                                  int* __restrict__ bsum) {
    __shared__ int lds[4];
    bool is_e = blockIdx.x < NB_E;
    const int* in = is_e ? hist_e : hist_n;
    int b = is_e ? blockIdx.x : blockIdx.x - NB_E;
    int n = is_e ? N_EDGES_C : N_NODES_C;
    int* bs = bsum + (is_e ? 0 : 128);
    int base = b * SCAN_CHUNK + threadIdx.x * SCAN_ITEMS;
    int s = 0;
#pragma unroll
    for (int j = 0; j < SCAN_ITEMS; ++j) {
        int idx = base + j;
        s += (idx < n) ? in[idx] : 0;
    }
    for (int d = 1; d < 64; d <<= 1) s += __shfl_xor(s, d);
    if ((threadIdx.x & 63) == 0) lds[threadIdx.x >> 6] = s;
    __syncthreads();
    if (threadIdx.x == 0) bs[b] = lds[0] + lds[1] + lds[2] + lds[3];
}

__device__ __forceinline__ void scan_seg(int* bs, int nb, int t) {
    int v0 = (2 * t < nb) ? bs[2 * t] : 0;
    int v1 = (2 * t + 1 < nb) ? bs[2 * t + 1] : 0;
    int s = v0 + v1;
    int incl = s;
    for (int d = 1; d < 64; d <<= 1) {
        int u = __shfl_up(incl, d);
        if (t >= d) incl += u;
    }
    int excl = incl - s;
    if (2 * t < nb) bs[2 * t] = excl;
    if (2 * t + 1 < nb) bs[2 * t + 1] = excl + v0;
}

// one block, 64 threads: exclusive-scan both bsum segments
__global__ void k_scan_bsum2(int* bsum) {
    int t = threadIdx.x;
    scan_seg(bsum, NB_E, t);
    scan_seg(bsum + 128, NB_N, t);
}

__global__ __launch_bounds__(256) void k_scan_write2(const int* __restrict__ hist_e,
                                                     const int* __restrict__ hist_n,
                                                     const int* __restrict__ bsum,
                                                     int* __restrict__ rpe,
                                                     int* __restrict__ rpn) {
    __shared__ int wsum[4];
    bool is_e = blockIdx.x < NB_E;
    const int* in = is_e ? hist_e : hist_n;
    int b = is_e ? blockIdx.x : blockIdx.x - NB_E;
    int n = is_e ? N_EDGES_C : N_NODES_C;
    const int* bs = bsum + (is_e ? 0 : 128);
    int* rowptr = is_e ? rpe : rpn;

    int tid = threadIdx.x;
    int base = b * SCAN_CHUNK + tid * SCAN_ITEMS;
    int v[SCAN_ITEMS];
    int s = 0;
#pragma unroll
    for (int j = 0; j < SCAN_ITEMS; ++j) {
        int idx = base + j;
        v[j] = (idx < n) ? in[idx] : 0;
        s += v[j];
    }
    int incl = s;
    int lane = tid & 63;
    for (int d = 1; d < 64; d <<= 1) {
        int u = __shfl_up(incl, d);
        if (lane >= d) incl += u;
    }
    if (lane == 63) wsum[tid >> 6] = incl;
    __syncthreads();
    int woff = 0;
    int w = tid >> 6;
    for (int i = 0; i < w; ++i) woff += wsum[i];
    int excl = woff + (incl - s) + bs[b];
#pragma unroll
    for (int j = 0; j < SCAN_ITEMS; ++j) {
        int idx = base + j;
        if (idx < n) rowptr[idx] = excl;
        excl += v[j];
    }
    if (b == 0 && tid == 0) rowptr[n] = N_INC_C;
}

// fused: blocks [0,PLACE_B) place both CSRs; blocks [PLACE_B,..) compute coef
#define PLACE_B 2048
__global__ void k_place_coef(const int* __restrict__ nidx, const int* __restrict__ eidx,
                             const int* __restrict__ rank_e, const int* __restrict__ rank_n,
                             const int* __restrict__ rpe, const int* __restrict__ rpn,
                             int* __restrict__ csr_e_n, int* __restrict__ csr_n_e,
                             const float* __restrict__ w, float* __restrict__ coef) {
    if (blockIdx.x >= PLACE_B) {
        int k = (blockIdx.x - PLACE_B) * 256 + threadIdx.x;
        if (k < N_EDGES_C) {
            int bd = rpe[k + 1] - rpe[k];
            coef[k] = (bd > 0) ? w[k] / (float)bd : 0.0f;
        }
        return;
    }
    int i = blockIdx.x * 256 + threadIdx.x;
    int stride = PLACE_B * 256;
    for (; i < N_INC_C; i += stride) {
        int n = nidx[i];
        int e = eidx[i];
        csr_e_n[rpe[e] + rank_e[i]] = n;
        csr_n_e[rpn[n] + rank_n[i]] = e;
    }
}

__global__ void k_dinv(const int* __restrict__ rpn, const int* __restrict__ csr_n_e,
                       const float* __restrict__ w, float* __restrict__ Dinv) {
    int i = blockIdx.x * blockDim.x + threadIdx.x;
    if (i >= N_NODES_C) return;
    int s0 = rpn[i], s1 = rpn[i + 1];
    float s = 0.0f;
    for (int k = s0; k < s1; ++k) s += w[csr_n_e[k]];
    Dinv[i] = (s > 0.0f) ? 1.0f / s : 0.0f;
}

// ---------------- register-tiled dense GEMM (fp32 compute) ----------------
template <int K, int N, int BM, int TM, int TN, int EPI, int OUTBF, int INBF>
__global__ __launch_bounds__(256) void k_gemm_rt(const void* __restrict__ Xv,
                                                 const float* __restrict__ W,
                                                 const float* __restrict__ bias,
                                                 void* __restrict__ Yv, int nrows) {
    static_assert(16 * TN == N && 16 * TM == BM, "tile mismatch");
    __shared__ float Ws[K * N];
    __shared__ float Xs[BM][K + 4];

    int tid = threadIdx.x;
    int row0 = blockIdx.x * BM;

    for (int t = tid * 4; t < K * N; t += 1024)
        *reinterpret_cast<float4*>(&Ws[t]) = *reinterpret_cast<const float4*>(&W[t]);

    if (INBF) {
        const ushort* X = (const ushort*)Xv;
        for (int t = tid * 8; t < BM * K; t += 2048) {
            int r = t / K, k = t % K;
            int gr = row0 + r;
            uint4 v = make_uint4(0, 0, 0, 0);
            if (gr < nrows) v = *reinterpret_cast<const uint4*>(&X[(size_t)gr * K + k]);
            unpack2(v.x, Xs[r][k + 0], Xs[r][k + 1]);
            unpack2(v.y, Xs[r][k + 2], Xs[r][k + 3]);
            unpack2(v.z, Xs[r][k + 4], Xs[r][k + 5]);
            unpack2(v.w, Xs[r][k + 6], Xs[r][k + 7]);
        }
    } else {
        const float* X = (const float*)Xv;
        for (int t = tid * 4; t < BM * K; t += 1024) {
            int r = t / K, k = t % K;
            int gr = row0 + r;
            float4 v;
            if (gr < nrows) v = *reinterpret_cast<const float4*>(&X[(size_t)gr * K + k]);
            else { v.x = v.y = v.z = v.w = 0.0f; }
            *reinterpret_cast<float4*>(&Xs[r][k]) = v;
        }
    }
    __syncthreads();

    int tx = tid & 15;
    int ty = tid >> 4;
    float acc[TM][TN] = {};
#pragma unroll 8
    for (int k = 0; k < K; ++k) {
        float a[TM], b[TN];
#pragma unroll
        for (int m = 0; m < TM; ++m) a[m] = Xs[ty * TM + m][k];
#pragma unroll
        for (int n = 0; n < TN; ++n) b[n] = Ws[k * N + tx * TN + n];
#pragma unroll
        for (int m = 0; m < TM; ++m)
#pragma unroll
            for (int n = 0; n < TN; ++n) acc[m][n] += a[m] * b[n];
    }

#pragma unroll
    for (int m = 0; m < TM; ++m) {
        int gr = row0 + ty * TM + m;
        if (gr >= nrows) continue;
        if (OUTBF) {
            ushort* Y = (ushort*)Yv;
            uint2 o;
            o.x = bfr(acc[m][0]) | (bfr(acc[m][1]) << 16);
            o.y = bfr(acc[m][2]) | (bfr(acc[m][3]) << 16);
            *reinterpret_cast<uint2*>(&Y[(size_t)gr * N + tx * TN]) = o;
        } else {
            float* Y = (float*)Yv;
#pragma unroll
            for (int ng = 0; ng < TN / 4; ++ng) {
                float4 o;
                o.x = acc[m][ng * 4 + 0]; o.y = acc[m][ng * 4 + 1];
                o.z = acc[m][ng * 4 + 2]; o.w = acc[m][ng * 4 + 3];
                if (EPI) {
                    const float4 b4 = *reinterpret_cast<const float4*>(&bias[tx * TN + ng * 4]);
                    o.x += b4.x; o.y += b4.y; o.z += b4.z; o.w += b4.w;
                    o.x = o.x > 0.0f ? o.x : 0.0f;
                    o.y = o.y > 0.0f ? o.y : 0.0f;
                    o.z = o.z > 0.0f ? o.z : 0.0f;
                    o.w = o.w > 0.0f ? o.w : 0.0f;
                }
                *reinterpret_cast<float4*>(&Y[(size_t)gr * N + tx * TN + ng * 4]) = o;
            }
        }
    }
}

// ---------------- unified bf16 CSR gather ----------------
// dst[r] = scale[r] * sum_{c in row} src[c]   (+bias, relu if FIN)
// scale = coef (node->edge rows) or Dinv (edge->node rows); per-ROW scalar,
// valid because Dinv*sum(coef*sum(h)) lets coef fold into the edge-row write.
// 8 neighbor-groups x 8 lanes x bf16x8; row = 64 bf16 = 128 B exactly.
template <int FIN>
__global__ __launch_bounds__(256) void k_gather_bf(const int* __restrict__ rowptr,
                                                   const int* __restrict__ cols,
                                                   const ushort* __restrict__ src,
                                                   const float* __restrict__ scale,
                                                   const float* __restrict__ bias,
                                                   ushort* __restrict__ dst, int nrows) {
    int wid = (blockIdx.x * 256 + threadIdx.x) >> 6;
    int lane = threadIdx.x & 63;
    int g = lane >> 3;        // neighbor group 0..7
    int gl = lane & 7;        // channels [gl*8, gl*8+8)
    int nw = (gridDim.x * 256) >> 6;
    for (int r = wid; r < nrows; r += nw) {
        int s0 = rowptr[r], s1 = rowptr[r + 1];
        float a[8] = {};
        for (int j = s0 + g; j < s1; j += 8) {
            int c = cols[j];  // uniform within group
            const uint4 v = *reinterpret_cast<const uint4*>(&src[(size_t)c * 64 + gl * 8]);
            float f0, f1;
            unpack2(v.x, f0, f1); a[0] += f0; a[1] += f1;
            unpack2(v.y, f0, f1); a[2] += f0; a[3] += f1;
            unpack2(v.z, f0, f1); a[4] += f0; a[5] += f1;
            unpack2(v.w, f0, f1); a[6] += f0; a[7] += f1;
        }
#pragma unroll
        for (int k = 0; k < 8; ++k) {
            a[k] += __shfl_xor(a[k], 8);
            a[k] += __shfl_xor(a[k], 16);
            a[k] += __shfl_xor(a[k], 32);
        }
        if (g == 0) {
            float sc = scale[r];
#pragma unroll
            for (int k = 0; k < 8; ++k) a[k] *= sc;
            if (FIN) {
                const float4 b0 = *reinterpret_cast<const float4*>(&bias[gl * 8]);
                const float4 b1v = *reinterpret_cast<const float4*>(&bias[gl * 8 + 4]);
                a[0] += b0.x; a[1] += b0.y; a[2] += b0.z; a[3] += b0.w;
                a[4] += b1v.x; a[5] += b1v.y; a[6] += b1v.z; a[7] += b1v.w;
#pragma unroll
                for (int k = 0; k < 8; ++k) a[k] = a[k] > 0.0f ? a[k] : 0.0f;
            }
            uint4 o;
            o.x = bfr(a[0]) | (bfr(a[1]) << 16);
            o.y = bfr(a[2]) | (bfr(a[3]) << 16);
            o.z = bfr(a[4]) | (bfr(a[5]) << 16);
            o.w = bfr(a[6]) | (bfr(a[7]) << 16);
            *reinterpret_cast<uint4*>(&dst[(size_t)r * 64 + gl * 8]) = o;
        }
    }
}

// ---------------- host ----------------

extern "C" void kernel_launch(void* const* d_in, const int* in_sizes, int n_in,
                              void* d_out, int out_size, void* d_ws, size_t ws_size,
                              hipStream_t stream) {
    const float* x   = (const float*)d_in[0];
    const int*   eix = (const int*)d_in[1];
    const float* w   = (const float*)d_in[2];
    const float* W1  = (const float*)d_in[4];
    const float* b1  = (const float*)d_in[5];
    const float* W2  = (const float*)d_in[6];
    const float* b2  = (const float*)d_in[7];
    float* out = (float*)d_out;

    const int* nidx = eix;
    const int* eidx = eix + N_INC_C;

    int*   wsI = (int*)d_ws;
    float* wsF = (float*)d_ws;
    int* hist_e  = wsI + U_HIST_E;
    int* hist_n  = wsI + U_HIST_N;
    int* rpe     = wsI + U_RPE;
    int* rpn     = wsI + U_RPN;
    int* bsum    = wsI + U_BSUM;
    float* coef  = wsF + U_COEF;
    float* Dinv  = wsF + U_DINV;
    int* rank_e  = wsI + U_RANK_E;
    int* rank_n  = wsI + U_RANK_N;
    int* csr_e_n = wsI + U_CSR_EN;
    int* csr_n_e = wsI + U_CSR_NE;
    ushort* nbuf = (ushort*)(wsI + U_R2);  // h1 / g1 / t2  [N_NODES x 64] bf16
    ushort* ebuf = (ushort*)(wsI + U_R1);  // e1 / s2       [N_EDGES x 64] bf16
    ushort* h1 = nbuf; ushort* g1 = nbuf; ushort* t2 = nbuf;
    ushort* e1 = ebuf; ushort* s2 = ebuf;

    // ---- CSR build ----
    hipMemsetAsync(wsI, 0, 300000 * sizeof(int), stream);  // hist_e + hist_n
    k_hist_rank<<<1600, 256, 0, stream>>>(nidx, eidx, hist_n, hist_e, rank_n, rank_e);

    k_scan_bs2<<<NB_E + NB_N, 256, 0, stream>>>(hist_e, hist_n, bsum);
    k_scan_bsum2<<<1, 64, 0, stream>>>(bsum);
    k_scan_write2<<<NB_E + NB_N, 256, 0, stream>>>(hist_e, hist_n, bsum, rpe, rpn);

    k_place_coef<<<PLACE_B + (N_EDGES_C + 255) / 256, 256, 0, stream>>>(
        nidx, eidx, rank_e, rank_n, rpe, rpn, csr_e_n, csr_n_e, w, coef);
    k_dinv<<<(N_NODES_C + 255) / 256, 256, 0, stream>>>(rpn, csr_n_e, w, Dinv);

    // ---- layer 1 ----
    k_gemm_rt<F_IN_C, H1_C, 32, 2, 4, 0, 1, 0><<<(N_NODES_C + 31) / 32, 256, 0, stream>>>(
        x, W1, nullptr, h1, N_NODES_C);
    k_gather_bf<0><<<(N_EDGES_C + 3) / 4, 256, 0, stream>>>(rpe, csr_e_n, h1, coef,
                                                            nullptr, e1, N_EDGES_C);
    k_gather_bf<1><<<(N_NODES_C + 3) / 4, 256, 0, stream>>>(rpn, csr_n_e, e1, Dinv,
                                                            b1, g1, N_NODES_C);

    // ---- layer 2 (aggregate in 64-dim, project 64->128 last) ----
    k_gather_bf<0><<<(N_EDGES_C + 3) / 4, 256, 0, stream>>>(rpe, csr_e_n, g1, coef,
                                                            nullptr, s2, N_EDGES_C);
    k_gather_bf<0><<<(N_NODES_C + 3) / 4, 256, 0, stream>>>(rpn, csr_n_e, s2, Dinv,
                                                            nullptr, t2, N_NODES_C);
    k_gemm_rt<H1_C, H2_C, 64, 4, 8, 1, 0, 1><<<(N_NODES_C + 63) / 64, 256, 0, stream>>>(
        t2, W2, b2, out, N_NODES_C);
}

// Round 14
// 453.470 us; speedup vs baseline: 1.0983x; 1.0983x over previous
//
#include <hip/hip_runtime.h>

// Problem constants
#define N_NODES_C 100000
#define N_EDGES_C 200000
#define N_INC_C   1600000
#define F_IN_C    128
#define H1_C      64
#define H2_C      128

typedef unsigned int uint;
typedef unsigned short ushort;

// ---------------- workspace layout (units of 4 bytes) ----------------
static constexpr size_t U_HIST_E = 0;          // 200000 (int)   memset [0,300000)
static constexpr size_t U_HIST_N = 200000;     // 100000 (int)
static constexpr size_t U_RPE    = 300000;     // 200001 (int)
static constexpr size_t U_RPN    = 500032;     // 100001 (int)
static constexpr size_t U_BSUM   = 600064;     // 256 (int): e at +0, n at +128
static constexpr size_t U_COEF   = 600320;     // 200000 (float)
static constexpr size_t U_DINV   = 800320;     // 100000 (float)
static constexpr size_t U_RANK_E = 900320;     // 1600000 (int)
static constexpr size_t U_RANK_N = 2500320;    // 1600000 (int)
static constexpr size_t U_CSR_EN = 4100320;    // 1600000 (int)  edge -> node ids
static constexpr size_t U_CSR_NE = 5700320;    // 1600000 (int)  node -> edge ids
static constexpr size_t U_R2     = 7300320;    // 3200000 u32 = node bf16 buf (h1/g1/t2)
static constexpr size_t U_R1     = 10500320;   // 6400000 u32 = edge bf16 buf (e1/s2)
// total = 16900320 * 4 B = 67.6 MB

// ---------------- bf16 helpers (fp32 accumulate, RNE pack) ----------------
__device__ __forceinline__ void unpack2(uint u, float& a, float& b) {
    a = __uint_as_float(u << 16);
    b = __uint_as_float(u & 0xFFFF0000u);
}
__device__ __forceinline__ uint bfr(float f) {
    uint u = __float_as_uint(f);
    return (u + 0x7FFFu + ((u >> 16) & 1u)) >> 16;
}

// ---------------- CSR build ----------------

// histogram + rank. [measured r11/r12]: ~25G atomics/s memory-side cap,
// insensitive to in-flight count (x4 unroll A/B was flat) — structural 130us.
__global__ void k_hist_rank(const int* __restrict__ nidx, const int* __restrict__ eidx,
                            int* __restrict__ hist_n, int* __restrict__ hist_e,
                            int* __restrict__ rank_n, int* __restrict__ rank_e) {
    int i = blockIdx.x * blockDim.x + threadIdx.x;
    int stride = gridDim.x * blockDim.x;
    for (; i < N_INC_C; i += stride) {
        rank_e[i] = atomicAdd(&hist_e[eidx[i]], 1);
        rank_n[i] = atomicAdd(&hist_n[nidx[i]], 1);
    }
}

#define SCAN_ITEMS 8
#define SCAN_CHUNK 2048  // 256 threads * 8
#define NB_E 98          // ceil(200000/2048)
#define NB_N 49          // ceil(100000/2048)

// merged e+n block-sum stage: blocks [0,NB_E) -> e, [NB_E,NB_E+NB_N) -> n
__global__ __launch_bounds__(256) void k_scan_bs2(const int* __restrict__ hist_e,
                                                  const int* __restrict__ hist_n,
                                                  int* __restrict__ bsum) {
    __shared__ int lds[4];
    bool is_e = blockIdx.x < NB_E;
    const int* in = is_e ? hist_e : hist_n;
    int b = is_e ? blockIdx.x : blockIdx.x - NB_E;
    int n = is_e ? N_EDGES_C : N_NODES_C;
    int* bs = bsum + (is_e ? 0 : 128);
    int base = b * SCAN_CHUNK + threadIdx.x * SCAN_ITEMS;
    int s = 0;
#pragma unroll
    for (int j = 0; j < SCAN_ITEMS; ++j) {
        int idx = base + j;
        s += (idx < n) ? in[idx] : 0;
    }
    for (int d = 1; d < 64; d <<= 1) s += __shfl_xor(s, d);
    if ((threadIdx.x & 63) == 0) lds[threadIdx.x >> 6] = s;
    __syncthreads();
    if (threadIdx.x == 0) bs[b] = lds[0] + lds[1] + lds[2] + lds[3];
}

__device__ __forceinline__ void scan_seg(int* bs, int nb, int t) {
    int v0 = (2 * t < nb) ? bs[2 * t] : 0;
    int v1 = (2 * t + 1 < nb) ? bs[2 * t + 1] : 0;
    int s = v0 + v1;
    int incl = s;
    for (int d = 1; d < 64; d <<= 1) {
        int u = __shfl_up(incl, d);
        if (t >= d) incl += u;
    }
    int excl = incl - s;
    if (2 * t < nb) bs[2 * t] = excl;
    if (2 * t + 1 < nb) bs[2 * t + 1] = excl + v0;
}

__global__ void k_scan_bsum2(int* bsum) {
    int t = threadIdx.x;
    scan_seg(bsum, NB_E, t);
    scan_seg(bsum + 128, NB_N, t);
}

__global__ __launch_bounds__(256) void k_scan_write2(const int* __restrict__ hist_e,
                                                     const int* __restrict__ hist_n,
                                                     const int* __restrict__ bsum,
                                                     int* __restrict__ rpe,
                                                     int* __restrict__ rpn) {
    __shared__ int wsum[4];
    bool is_e = blockIdx.x < NB_E;
    const int* in = is_e ? hist_e : hist_n;
    int b = is_e ? blockIdx.x : blockIdx.x - NB_E;
    int n = is_e ? N_EDGES_C : N_NODES_C;
    const int* bs = bsum + (is_e ? 0 : 128);
    int* rowptr = is_e ? rpe : rpn;

    int tid = threadIdx.x;
    int base = b * SCAN_CHUNK + tid * SCAN_ITEMS;
    int v[SCAN_ITEMS];
    int s = 0;
#pragma unroll
    for (int j = 0; j < SCAN_ITEMS; ++j) {
        int idx = base + j;
        v[j] = (idx < n) ? in[idx] : 0;
        s += v[j];
    }
    int incl = s;
    int lane = tid & 63;
    for (int d = 1; d < 64; d <<= 1) {
        int u = __shfl_up(incl, d);
        if (lane >= d) incl += u;
    }
    if (lane == 63) wsum[tid >> 6] = incl;
    __syncthreads();
    int woff = 0;
    int w = tid >> 6;
    for (int i = 0; i < w; ++i) woff += wsum[i];
    int excl = woff + (incl - s) + bs[b];
#pragma unroll
    for (int j = 0; j < SCAN_ITEMS; ++j) {
        int idx = base + j;
        if (idx < n) rowptr[idx] = excl;
        excl += v[j];
    }
    if (b == 0 && tid == 0) rowptr[n] = N_INC_C;
}

// fused: blocks [0,PLACE_B) place both CSRs; blocks [PLACE_B,..) compute coef
#define PLACE_B 2048
__global__ void k_place_coef(const int* __restrict__ nidx, const int* __restrict__ eidx,
                             const int* __restrict__ rank_e, const int* __restrict__ rank_n,
                             const int* __restrict__ rpe, const int* __restrict__ rpn,
                             int* __restrict__ csr_e_n, int* __restrict__ csr_n_e,
                             const float* __restrict__ w, float* __restrict__ coef) {
    if (blockIdx.x >= PLACE_B) {
        int k = (blockIdx.x - PLACE_B) * 256 + threadIdx.x;
        if (k < N_EDGES_C) {
            int bd = rpe[k + 1] - rpe[k];
            coef[k] = (bd > 0) ? w[k] / (float)bd : 0.0f;
        }
        return;
    }
    int i = blockIdx.x * 256 + threadIdx.x;
    int stride = PLACE_B * 256;
    for (; i < N_INC_C; i += stride) {
        int n = nidx[i];
        int e = eidx[i];
        csr_e_n[rpe[e] + rank_e[i]] = n;
        csr_n_e[rpn[n] + rank_n[i]] = e;
    }
}

// wave-parallel Dinv: 8 nodes/wave, 8 lanes/node.
// Grid MUST cover ceil(N_NODES/32) blocks (32 nodes/block) — r13 bug was 392 blocks.
__global__ __launch_bounds__(256) void k_dinv(const int* __restrict__ rpn,
                                              const int* __restrict__ csr_n_e,
                                              const float* __restrict__ w,
                                              float* __restrict__ Dinv) {
    int wid = (blockIdx.x * 256 + threadIdx.x) >> 6;
    int lane = threadIdx.x & 63;
    int g = lane >> 3;   // node slot 0..7
    int gl = lane & 7;   // neighbor lane
    int node = wid * 8 + g;
    if (node >= N_NODES_C) return;
    int s0 = rpn[node], s1 = rpn[node + 1];
    float s = 0.0f;
    for (int j = s0 + gl; j < s1; j += 8) s += w[csr_n_e[j]];
    s += __shfl_xor(s, 1);
    s += __shfl_xor(s, 2);
    s += __shfl_xor(s, 4);
    if (gl == 0) Dinv[node] = (s > 0.0f) ? 1.0f / s : 0.0f;
}

// ---------------- register-tiled dense GEMM (fp32 compute) ----------------
template <int K, int N, int BM, int TM, int TN, int EPI, int OUTBF, int INBF>
__global__ __launch_bounds__(256) void k_gemm_rt(const void* __restrict__ Xv,
                                                 const float* __restrict__ W,
                                                 const float* __restrict__ bias,
                                                 void* __restrict__ Yv, int nrows) {
    static_assert(16 * TN == N && 16 * TM == BM, "tile mismatch");
    __shared__ float Ws[K * N];
    __shared__ float Xs[BM][K + 4];

    int tid = threadIdx.x;
    int row0 = blockIdx.x * BM;

    for (int t = tid * 4; t < K * N; t += 1024)
        *reinterpret_cast<float4*>(&Ws[t]) = *reinterpret_cast<const float4*>(&W[t]);

    if (INBF) {
        const ushort* X = (const ushort*)Xv;
        for (int t = tid * 8; t < BM * K; t += 2048) {
            int r = t / K, k = t % K;
            int gr = row0 + r;
            uint4 v = make_uint4(0, 0, 0, 0);
            if (gr < nrows) v = *reinterpret_cast<const uint4*>(&X[(size_t)gr * K + k]);
            unpack2(v.x, Xs[r][k + 0], Xs[r][k + 1]);
            unpack2(v.y, Xs[r][k + 2], Xs[r][k + 3]);
            unpack2(v.z, Xs[r][k + 4], Xs[r][k + 5]);
            unpack2(v.w, Xs[r][k + 6], Xs[r][k + 7]);
        }
    } else {
        const float* X = (const float*)Xv;
        for (int t = tid * 4; t < BM * K; t += 1024) {
            int r = t / K, k = t % K;
            int gr = row0 + r;
            float4 v;
            if (gr < nrows) v = *reinterpret_cast<const float4*>(&X[(size_t)gr * K + k]);
            else { v.x = v.y = v.z = v.w = 0.0f; }
            *reinterpret_cast<float4*>(&Xs[r][k]) = v;
        }
    }
    __syncthreads();

    int tx = tid & 15;
    int ty = tid >> 4;
    float acc[TM][TN] = {};
#pragma unroll 8
    for (int k = 0; k < K; ++k) {
        float a[TM], b[TN];
#pragma unroll
        for (int m = 0; m < TM; ++m) a[m] = Xs[ty * TM + m][k];
#pragma unroll
        for (int n = 0; n < TN; ++n) b[n] = Ws[k * N + tx * TN + n];
#pragma unroll
        for (int m = 0; m < TM; ++m)
#pragma unroll
            for (int n = 0; n < TN; ++n) acc[m][n] += a[m] * b[n];
    }

#pragma unroll
    for (int m = 0; m < TM; ++m) {
        int gr = row0 + ty * TM + m;
        if (gr >= nrows) continue;
        if (OUTBF) {
            ushort* Y = (ushort*)Yv;
            uint2 o;
            o.x = bfr(acc[m][0]) | (bfr(acc[m][1]) << 16);
            o.y = bfr(acc[m][2]) | (bfr(acc[m][3]) << 16);
            *reinterpret_cast<uint2*>(&Y[(size_t)gr * N + tx * TN]) = o;
        } else {
            float* Y = (float*)Yv;
#pragma unroll
            for (int ng = 0; ng < TN / 4; ++ng) {
                float4 o;
                o.x = acc[m][ng * 4 + 0]; o.y = acc[m][ng * 4 + 1];
                o.z = acc[m][ng * 4 + 2]; o.w = acc[m][ng * 4 + 3];
                if (EPI) {
                    const float4 b4 = *reinterpret_cast<const float4*>(&bias[tx * TN + ng * 4]);
                    o.x += b4.x; o.y += b4.y; o.z += b4.z; o.w += b4.w;
                    o.x = o.x > 0.0f ? o.x : 0.0f;
                    o.y = o.y > 0.0f ? o.y : 0.0f;
                    o.z = o.z > 0.0f ? o.z : 0.0f;
                    o.w = o.w > 0.0f ? o.w : 0.0f;
                }
                *reinterpret_cast<float4*>(&Y[(size_t)gr * N + tx * TN + ng * 4]) = o;
            }
        }
    }
}

// ---------------- unified bf16 CSR gather, DUAL-ROW ----------------
// Each wave processes rows 2w and 2w+1 with interleaved loads (2x MLP);
// dst[r] = scale[r] * sum_{c in row} src[c]  (+bias, relu if FIN)
// 8 neighbor-groups x 8 lanes x bf16x8; row = 64 bf16 = 128 B exactly.
template <int FIN>
__global__ __launch_bounds__(256) void k_gather_bf2(const int* __restrict__ rowptr,
                                                    const int* __restrict__ cols,
                                                    const ushort* __restrict__ src,
                                                    const float* __restrict__ scale,
                                                    const float* __restrict__ bias,
                                                    ushort* __restrict__ dst, int nrows) {
    int wid = (blockIdx.x * 256 + threadIdx.x) >> 6;
    int lane = threadIdx.x & 63;
    int g = lane >> 3;        // neighbor group 0..7
    int gl = lane & 7;        // channels [gl*8, gl*8+8)
    int rA = wid * 2;
    if (rA >= nrows) return;
    int rB = rA + 1;
    bool hasB = rB < nrows;

    int a0 = rowptr[rA], a1 = rowptr[rA + 1];
    int b0 = 0, b1 = 0;
    if (hasB) { b0 = a1; b1 = rowptr[rB + 1]; }  // rows contiguous in CSR

    float aA[8] = {}, aB[8] = {};
    int jA = a0 + g, jB = b0 + g;
    while (jA < a1 || jB < b1) {
        int cA = (jA < a1) ? cols[jA] : -1;
        int cB = (jB < b1) ? cols[jB] : -1;
        if (cA >= 0) {
            const uint4 v = *reinterpret_cast<const uint4*>(&src[(size_t)cA * 64 + gl * 8]);
            float f0, f1;
            unpack2(v.x, f0, f1); aA[0] += f0; aA[1] += f1;
            unpack2(v.y, f0, f1); aA[2] += f0; aA[3] += f1;
            unpack2(v.z, f0, f1); aA[4] += f0; aA[5] += f1;
            unpack2(v.w, f0, f1); aA[6] += f0; aA[7] += f1;
        }
        if (cB >= 0) {
            const uint4 v = *reinterpret_cast<const uint4*>(&src[(size_t)cB * 64 + gl * 8]);
            float f0, f1;
            unpack2(v.x, f0, f1); aB[0] += f0; aB[1] += f1;
            unpack2(v.y, f0, f1); aB[2] += f0; aB[3] += f1;
            unpack2(v.z, f0, f1); aB[4] += f0; aB[5] += f1;
            unpack2(v.w, f0, f1); aB[6] += f0; aB[7] += f1;
        }
        jA += 8; jB += 8;
    }
#pragma unroll
    for (int k = 0; k < 8; ++k) {
        aA[k] += __shfl_xor(aA[k], 8);
        aA[k] += __shfl_xor(aA[k], 16);
        aA[k] += __shfl_xor(aA[k], 32);
        aB[k] += __shfl_xor(aB[k], 8);
        aB[k] += __shfl_xor(aB[k], 16);
        aB[k] += __shfl_xor(aB[k], 32);
    }
    // g==0 writes row A; g==1 writes row B
    if (g <= 1) {
        int r = (g == 0) ? rA : rB;
        if (g == 1 && !hasB) return;
        float* a = (g == 0) ? aA : aB;
        float sc = scale[r];
#pragma unroll
        for (int k = 0; k < 8; ++k) a[k] *= sc;
        if (FIN) {
            const float4 bb0 = *reinterpret_cast<const float4*>(&bias[gl * 8]);
            const float4 bb1 = *reinterpret_cast<const float4*>(&bias[gl * 8 + 4]);
            a[0] += bb0.x; a[1] += bb0.y; a[2] += bb0.z; a[3] += bb0.w;
            a[4] += bb1.x; a[5] += bb1.y; a[6] += bb1.z; a[7] += bb1.w;
#pragma unroll
            for (int k = 0; k < 8; ++k) a[k] = a[k] > 0.0f ? a[k] : 0.0f;
        }
        uint4 o;
        o.x = bfr(a[0]) | (bfr(a[1]) << 16);
        o.y = bfr(a[2]) | (bfr(a[3]) << 16);
        o.z = bfr(a[4]) | (bfr(a[5]) << 16);
        o.w = bfr(a[6]) | (bfr(a[7]) << 16);
        *reinterpret_cast<uint4*>(&dst[(size_t)r * 64 + gl * 8]) = o;
    }
}

// ---------------- host ----------------

extern "C" void kernel_launch(void* const* d_in, const int* in_sizes, int n_in,
                              void* d_out, int out_size, void* d_ws, size_t ws_size,
                              hipStream_t stream) {
    const float* x   = (const float*)d_in[0];
    const int*   eix = (const int*)d_in[1];
    const float* w   = (const float*)d_in[2];
    const float* W1  = (const float*)d_in[4];
    const float* b1  = (const float*)d_in[5];
    const float* W2  = (const float*)d_in[6];
    const float* b2  = (const float*)d_in[7];
    float* out = (float*)d_out;

    const int* nidx = eix;
    const int* eidx = eix + N_INC_C;

    int*   wsI = (int*)d_ws;
    float* wsF = (float*)d_ws;
    int* hist_e  = wsI + U_HIST_E;
    int* hist_n  = wsI + U_HIST_N;
    int* rpe     = wsI + U_RPE;
    int* rpn     = wsI + U_RPN;
    int* bsum    = wsI + U_BSUM;
    float* coef  = wsF + U_COEF;
    float* Dinv  = wsF + U_DINV;
    int* rank_e  = wsI + U_RANK_E;
    int* rank_n  = wsI + U_RANK_N;
    int* csr_e_n = wsI + U_CSR_EN;
    int* csr_n_e = wsI + U_CSR_NE;
    ushort* nbuf = (ushort*)(wsI + U_R2);  // h1 / g1 / t2  [N_NODES x 64] bf16
    ushort* ebuf = (ushort*)(wsI + U_R1);  // e1 / s2       [N_EDGES x 64] bf16
    ushort* h1 = nbuf; ushort* g1 = nbuf; ushort* t2 = nbuf;
    ushort* e1 = ebuf; ushort* s2 = ebuf;

    // ---- CSR build ----
    hipMemsetAsync(wsI, 0, 300000 * sizeof(int), stream);  // hist_e + hist_n
    k_hist_rank<<<2048, 256, 0, stream>>>(nidx, eidx, hist_n, hist_e, rank_n, rank_e);

    k_scan_bs2<<<NB_E + NB_N, 256, 0, stream>>>(hist_e, hist_n, bsum);
    k_scan_bsum2<<<1, 64, 0, stream>>>(bsum);
    k_scan_write2<<<NB_E + NB_N, 256, 0, stream>>>(hist_e, hist_n, bsum, rpe, rpn);

    k_place_coef<<<PLACE_B + (N_EDGES_C + 255) / 256, 256, 0, stream>>>(
        nidx, eidx, rank_e, rank_n, rpe, rpn, csr_e_n, csr_n_e, w, coef);
    k_dinv<<<(N_NODES_C + 31) / 32, 256, 0, stream>>>(rpn, csr_n_e, w, Dinv);

    // ---- layer 1 ----
    k_gemm_rt<F_IN_C, H1_C, 32, 2, 4, 0, 1, 0><<<(N_NODES_C + 31) / 32, 256, 0, stream>>>(
        x, W1, nullptr, h1, N_NODES_C);
    k_gather_bf2<0><<<(N_EDGES_C + 7) / 8, 256, 0, stream>>>(rpe, csr_e_n, h1, coef,
                                                             nullptr, e1, N_EDGES_C);
    k_gather_bf2<1><<<(N_NODES_C + 7) / 8, 256, 0, stream>>>(rpn, csr_n_e, e1, Dinv,
                                                             b1, g1, N_NODES_C);

    // ---- layer 2 (aggregate in 64-dim, project 64->128 last) ----
    k_gather_bf2<0><<<(N_EDGES_C + 7) / 8, 256, 0, stream>>>(rpe, csr_e_n, g1, coef,
                                                             nullptr, s2, N_EDGES_C);
    k_gather_bf2<0><<<(N_NODES_C + 7) / 8, 256, 0, stream>>>(rpn, csr_n_e, s2, Dinv,
                                                             nullptr, t2, N_NODES_C);
    k_gemm_rt<H1_C, H2_C, 64, 4, 8, 1, 0, 1><<<(N_NODES_C + 63) / 64, 256, 0, stream>>>(
        t2, W2, b2, out, N_NODES_C);
}